// Round 10
// baseline (495.944 us; speedup 1.0000x reference)
//
#include <hip/hip_runtime.h>

#define BTOT 131072
#define TSEQ 15
#define BM   32

typedef __attribute__((ext_vector_type(8))) _Float16 f16x8;
typedef __attribute__((ext_vector_type(2))) __fp16 fp16x2_raw;  // builtin's return type
typedef __attribute__((ext_vector_type(4))) float f32x4;

// Activation on PRESCALED gates: gi,gf,go arrive ×(-log2 e), gg arrives ×(2 log2 e),
// folded into weights/biases, so exp2 args are the raw MFMA outputs.
__device__ __forceinline__ void lstm_act_ps(float gi, float gf, float gg, float go,
                                            float& c, float& h){
  const float P2L2E = 2.8853900817779268f;   // 2*log2(e)
  float ei = __builtin_amdgcn_exp2f(gi);
  float ef = __builtin_amdgcn_exp2f(gf);
  float eg = __builtin_amdgcn_exp2f(gg);
  float Df = 1.f + ef, Di = 1.f + ei, Dg = 1.f + eg;
  float DiDg = Di*Dg;
  float r  = __builtin_amdgcn_rcpf(Df*DiDg);
  float sf = DiDg*r;                         // sigmoid(f)
  float ig = ((eg-1.f)*Df)*r;                // sigmoid(i)*tanh(g)
  c = __builtin_fmaf(sf, c, ig);
  float eo = __builtin_amdgcn_exp2f(go);
  float ec = __builtin_amdgcn_exp2f(c * P2L2E);
  float r2 = __builtin_amdgcn_rcpf((1.f+eo)*(1.f+ec));
  h = (ec-1.f)*r2;                           // sigmoid(o)*tanh(c)
}

// pack 2 f32 -> 2 f16 (1 instr) and store to two swizzled LDS rows
__device__ __forceinline__ void store_h2(char* base, int row0, int colb,
                                         float v0, float v1){
  union { fp16x2_raw h; unsigned u; } p;
  p.h = __builtin_amdgcn_cvt_pkrtz(v0, v1);
  int off0 = (( row0   *128 + colb) ^ (( row0   &7)<<4));
  int off1 = (((row0+1)*128 + colb) ^ (((row0+1)&7)<<4));
  *(short*)(base + off0) = (short)(p.u & 0xffffu);
  *(short*)(base + off1) = (short)(p.u >> 16);
}

// ---------------- kernel 1: per-timestep batch statistics ----------------
#define RPB 512
__global__ __launch_bounds__(256) void bn_stats(const float* __restrict__ x,
                                                float* __restrict__ sums){
  __shared__ float buf[RPB*TSEQ];            // 30720 B
  const int tid = threadIdx.x;
  const float4* src = (const float4*)(x + (size_t)blockIdx.x * (RPB*TSEQ));
  float4* dst = (float4*)buf;
  #pragma unroll
  for (int i=0;i<8;i++){
    int idx = tid + i*256;
    if (idx < RPB*TSEQ/4) dst[idx] = src[idx];
  }
  __syncthreads();
  float s[TSEQ], s2[TSEQ];
  #pragma unroll
  for (int t=0;t<TSEQ;t++){ s[t]=0.f; s2[t]=0.f; }
  #pragma unroll
  for (int rr=0; rr<RPB/256; rr++){
    const float* row = buf + (tid*(RPB/256)+rr)*TSEQ;
    #pragma unroll
    for (int t=0;t<TSEQ;t++){ float v=row[t]; s[t]+=v; s2[t]=__builtin_fmaf(v,v,s2[t]); }
  }
  #pragma unroll
  for (int t=0;t<TSEQ;t++){
    #pragma unroll
    for (int off=32; off>0; off>>=1){
      s[t]  += __shfl_down(s[t],  off, 64);
      s2[t] += __shfl_down(s2[t], off, 64);
    }
  }
  __syncthreads();                           // buf reads done; reuse for partials
  const int w = tid>>6, lane = tid&63;
  if (lane==0){
    #pragma unroll
    for (int t=0;t<TSEQ;t++){ buf[w*32+t]=s[t]; buf[w*32+16+t]=s2[t]; }
  }
  __syncthreads();
  if (tid < 2*TSEQ){
    int g = (tid < TSEQ) ? tid : (tid - TSEQ + 16);
    float a = buf[g] + buf[32+g] + buf[64+g] + buf[96+g];
    atomicAdd(&sums[tid], a);
  }
}

// ---------------- kernel 2: fused BN + 2-layer LSTM + FC ----------------
// Region t computes L1(t-1) THEN L0(t) reusing ONE acc set, ONE barrier/step.
// Two live acc sets spill (rounds 4/5); BM=64 spills (round 8); keep BM=32,
// ONE acc set. NO 2nd launch_bounds arg: (256,2) appears to PIN waves/EU at 2
// (rounds 1/3/7/9 all read 22% occupancy regardless of footprint); (256,3)
// sets a 256/3=85-reg budget and spills (round 2). Unconstrained lets the
// allocator find its own occupancy.
__global__ __launch_bounds__(256) void lstm_fused(
    const float* __restrict__ x,
    const float* __restrict__ gamma, const float* __restrict__ beta,
    const float* __restrict__ Wih0,  const float* __restrict__ Whh0,
    const float* __restrict__ bih0,  const float* __restrict__ bhh0,
    const float* __restrict__ Wih1,  const float* __restrict__ Whh1,
    const float* __restrict__ bih1,  const float* __restrict__ bhh1,
    const float* __restrict__ Wfc,   const float* __restrict__ bfc,
    const float* __restrict__ sums,  float* __restrict__ out)
{
  // double-buffered h tiles (f16): h0(t)->h0s[(t&1)*2048]; row stride 128B, XOR-swizzled
  __shared__ alignas(16) short h0s[2*BM*64];
  __shared__ alignas(16) short h1s[2*BM*64];
  __shared__ float xns[BM][17];              // stride 17: no bank conflict
  __shared__ float scs[TSEQ], shs[TSEQ];

  const int tid  = threadIdx.x;
  const int w    = tid >> 6;        // wave id 0..3 -> owns h columns [w*16, w*16+16)
  const int lane = tid & 63;
  const int l15  = lane & 15;
  const int lg   = lane >> 4;
  const int rbase = blockIdx.x * BM;

  if (tid < TSEQ){
    const float inv = 1.f/(float)BTOT;
    float mean = sums[tid]*inv;
    float var  = sums[TSEQ+tid]*inv - mean*mean;
    float sc = gamma[tid] * rsqrtf(var + 1e-5f);
    scs[tid] = sc;
    shs[tid] = beta[tid] - mean*sc;
  }
  // only h1(-1) (odd buffer of h1s) is read before being written
  #pragma unroll
  for (int i=0;i<8;i++) h1s[2048 + tid + i*256] = 0;
  __syncthreads();
  for (int i = tid; i < BM*TSEQ; i += 256){
    int r = i/TSEQ, t = i - r*TSEQ;
    xns[r][t] = x[(rbase+r)*TSEQ + t] * scs[t] + shs[t];
  }

  // ---- per-lane constants & weight B-fragments (registers, f16, PRESCALED) ----
  const float NL2E = -1.4426950408889634f, P2L2E = 2.8853900817779268f;
  float wx0[4], bs0[4], bs1[4];
  f16x8 wB0[2][4], wB1[4][4];
  #pragma unroll
  for (int n=0;n<4;n++){
    const float ks = (n==2) ? P2L2E : NL2E;  // gate order i,f,g,o
    int g = n*64 + w*16 + l15;               // gate column (block n)
    wx0[n] = Wih0[g]*ks;
    bs0[n] = (bih0[g] + bhh0[g])*ks;
    bs1[n] = (bih1[g] + bhh1[g])*ks;
    #pragma unroll
    for (int kk=0;kk<2;kk++){
      const float* p = Whh0 + g*64 + kk*32 + lg*8;
      #pragma unroll
      for (int e=0;e<8;e++) wB0[kk][n][e] = (_Float16)(p[e]*ks);
    }
    #pragma unroll
    for (int kk=0;kk<4;kk++){                // combined K=128: [W_ih1 | W_hh1]
      const float* bsrc = (kk<2) ? Wih1 : Whh1;
      const float* p = bsrc + g*64 + (kk&1)*32 + lg*8;
      #pragma unroll
      for (int e=0;e<8;e++) wB1[kk][n][e] = (_Float16)(p[e]*ks);
    }
  }

  // cell state in MFMA C-layout: row = m*16 + lg*4 + r, col = w*16 + l15
  f32x4 c0[2], c1[2];
  #pragma unroll
  for (int m=0;m<2;m++){
    c0[m] = (f32x4){0.f,0.f,0.f,0.f};
    c1[m] = (f32x4){0.f,0.f,0.f,0.f};
  }

  const int colb = (w*16 + l15)*2;           // write column byte offset

  __syncthreads();

  // ---- prologue: layer0(t=0), h0(-1)=0 so no recurrent MFMA; h0(0)->h0s[0]
  #pragma unroll
  for (int m=0;m<2;m++){
    float hv[4];
    #pragma unroll
    for (int r=0;r<4;r++){
      float xv = xns[m*16 + lg*4 + r][0];
      float g0 = __builtin_fmaf(xv, wx0[0], bs0[0]);
      float g1 = __builtin_fmaf(xv, wx0[1], bs0[1]);
      float g2 = __builtin_fmaf(xv, wx0[2], bs0[2]);
      float g3 = __builtin_fmaf(xv, wx0[3], bs0[3]);
      float c = c0[m][r];
      lstm_act_ps(g0, g1, g2, g3, c, hv[r]);
      c0[m][r] = c;
    }
    int row0 = m*16 + lg*4;
    store_h2((char*)h0s, row0,   colb, hv[0], hv[1]);
    store_h2((char*)h0s, row0+2, colb, hv[2], hv[3]);
  }
  __syncthreads();

  // ---- main loop: region t = L1(t-1) then L0(t), ONE barrier, ONE acc set ----
  #pragma unroll 2
  for (int t=1; t<TSEQ; t++){
    const int b0r = ((t-1)&1)*2048;   // h0(t-1)
    const int b0w = (t&1)*2048;       // h0(t)
    const int b1r = (t&1)*2048;       // h1(t-2)
    const int b1w = ((t-1)&1)*2048;   // h1(t-1)
    {
      // ----- layer1(t-1): gates = bias + [h0(t-1) | h1(t-2)] @ [Wih1|Whh1]^T
      f32x4 acc[2][4];
      #pragma unroll
      for (int m=0;m<2;m++)
        #pragma unroll
        for (int n=0;n<4;n++)
          #pragma unroll
          for (int r=0;r<4;r++)
            acc[m][n][r] = bs1[n];
      #pragma unroll
      for (int kk=0;kk<4;kk++){
        const short* asrc = (kk<2) ? (h0s+b0r) : (h1s+b1r);
        #pragma unroll
        for (int m=0;m<2;m++){
          int row = m*16 + l15;
          int off = ((row*128 + (kk&1)*64 + lg*16) ^ ((row&7)<<4));
          f16x8 a = *(const f16x8*)((const char*)asrc + off);
          #pragma unroll
          for (int n=0;n<4;n++)
            acc[m][n] = __builtin_amdgcn_mfma_f32_16x16x32_f16(a, wB1[kk][n], acc[m][n], 0,0,0);
        }
      }
      #pragma unroll
      for (int m=0;m<2;m++){
        float hv[4];
        #pragma unroll
        for (int r=0;r<4;r++){
          float c = c1[m][r];
          lstm_act_ps(acc[m][0][r], acc[m][1][r], acc[m][2][r], acc[m][3][r], c, hv[r]);
          c1[m][r] = c;
        }
        int row0 = m*16 + lg*4;
        store_h2((char*)(h1s+b1w), row0,   colb, hv[0], hv[1]);
        store_h2((char*)(h1s+b1w), row0+2, colb, hv[2], hv[3]);
      }
    }
    {
      // ----- layer0(t): gates = bias + xn(t)*W_ih0 + h0(t-1) @ Whh0^T
      f32x4 acc[2][4];
      #pragma unroll
      for (int m=0;m<2;m++){
        #pragma unroll
        for (int r=0;r<4;r++){
          float xv = xns[m*16 + lg*4 + r][t];
          #pragma unroll
          for (int n=0;n<4;n++) acc[m][n][r] = __builtin_fmaf(xv, wx0[n], bs0[n]);
        }
      }
      #pragma unroll
      for (int kk=0;kk<2;kk++){
        #pragma unroll
        for (int m=0;m<2;m++){
          int row = m*16 + l15;
          int off = ((row*128 + kk*64 + lg*16) ^ ((row&7)<<4));
          f16x8 a = *(const f16x8*)((const char*)(h0s+b0r) + off);
          #pragma unroll
          for (int n=0;n<4;n++)
            acc[m][n] = __builtin_amdgcn_mfma_f32_16x16x32_f16(a, wB0[kk][n], acc[m][n], 0,0,0);
        }
      }
      #pragma unroll
      for (int m=0;m<2;m++){
        float hv[4];
        #pragma unroll
        for (int r=0;r<4;r++){
          float c = c0[m][r];
          lstm_act_ps(acc[m][0][r], acc[m][1][r], acc[m][2][r], acc[m][3][r], c, hv[r]);
          c0[m][r] = c;
        }
        int row0 = m*16 + lg*4;
        store_h2((char*)(h0s+b0w), row0,   colb, hv[0], hv[1]);
        store_h2((char*)(h0s+b0w), row0+2, colb, hv[2], hv[3]);
      }
    }
    __syncthreads();   // publish h1(t-1) and h0(t)
  }

  // ---- epilogue: layer1(14): reads h0(14)=h0s[0], h1(13)=h1s[2048]; writes h1(14)->h1s[0]
  {
    f32x4 acc[2][4];
    #pragma unroll
    for (int m=0;m<2;m++)
      #pragma unroll
      for (int n=0;n<4;n++)
        #pragma unroll
        for (int r=0;r<4;r++)
          acc[m][n][r] = bs1[n];
    #pragma unroll
    for (int kk=0;kk<4;kk++){
      const short* asrc = (kk<2) ? (h0s+0) : (h1s+2048);
      #pragma unroll
      for (int m=0;m<2;m++){
        int row = m*16 + l15;
        int off = ((row*128 + (kk&1)*64 + lg*16) ^ ((row&7)<<4));
        f16x8 a = *(const f16x8*)((const char*)asrc + off);
        #pragma unroll
        for (int n=0;n<4;n++)
          acc[m][n] = __builtin_amdgcn_mfma_f32_16x16x32_f16(a, wB1[kk][n], acc[m][n], 0,0,0);
      }
    }
    #pragma unroll
    for (int m=0;m<2;m++){
      float hv[4];
      #pragma unroll
      for (int r=0;r<4;r++){
        float c = c1[m][r];
        lstm_act_ps(acc[m][0][r], acc[m][1][r], acc[m][2][r], acc[m][3][r], c, hv[r]);
      }
      int row0 = m*16 + lg*4;
      store_h2((char*)h1s, row0,   colb, hv[0], hv[1]);
      store_h2((char*)h1s, row0+2, colb, hv[2], hv[3]);
    }
  }
  __syncthreads();

  // ----- FC: out = relu(h1(14) @ Wfc^T + bfc); wFC loaded HERE (not loop-carried)
  f16x8 wFC[2];
  float fcb;
  {
    int o = w*16 + l15;
    fcb = bfc[o];
    #pragma unroll
    for (int kk=0;kk<2;kk++){
      const float* p = Wfc + o*64 + kk*32 + lg*8;
      #pragma unroll
      for (int e=0;e<8;e++) wFC[kk][e] = (_Float16)p[e];
    }
  }
  f32x4 accF[2];
  #pragma unroll
  for (int m=0;m<2;m++)
    #pragma unroll
    for (int r=0;r<4;r++) accF[m][r] = fcb;
  #pragma unroll
  for (int kk=0;kk<2;kk++){
    #pragma unroll
    for (int m=0;m<2;m++){
      int row = m*16 + l15;
      int off = ((row*128 + kk*64 + lg*16) ^ ((row&7)<<4));
      f16x8 a = *(const f16x8*)((const char*)h1s + off);
      accF[m] = __builtin_amdgcn_mfma_f32_16x16x32_f16(a, wFC[kk], accF[m], 0,0,0);
    }
  }
  #pragma unroll
  for (int m=0;m<2;m++){
    #pragma unroll
    for (int r=0;r<4;r++){
      float v = accF[m][r];
      v = v > 0.f ? v : 0.f;
      out[(rbase + m*16 + lg*4 + r)*64 + w*16 + l15] = v;
    }
  }
}

extern "C" void kernel_launch(void* const* d_in, const int* in_sizes, int n_in,
                              void* d_out, int out_size, void* d_ws, size_t ws_size,
                              hipStream_t stream) {
  const float* x     = (const float*)d_in[0];
  const float* gamma = (const float*)d_in[1];
  const float* beta  = (const float*)d_in[2];
  const float* Wih0  = (const float*)d_in[3];
  const float* Whh0  = (const float*)d_in[4];
  const float* bih0  = (const float*)d_in[5];
  const float* bhh0  = (const float*)d_in[6];
  const float* Wih1  = (const float*)d_in[7];
  const float* Whh1  = (const float*)d_in[8];
  const float* bih1  = (const float*)d_in[9];
  const float* bhh1  = (const float*)d_in[10];
  const float* Wfc   = (const float*)d_in[11];
  const float* bfc   = (const float*)d_in[12];
  float* sums = (float*)d_ws;
  float* out  = (float*)d_out;

  (void)hipMemsetAsync(d_ws, 0, 2*TSEQ*sizeof(float), stream);
  bn_stats<<<dim3(BTOT/RPB), dim3(256), 0, stream>>>(x, sums);
  lstm_fused<<<dim3(BTOT/BM), dim3(256), 0, stream>>>(
      x, gamma, beta, Wih0, Whh0, bih0, bhh0,
      Wih1, Whh1, bih1, bhh1, Wfc, bfc, sums, out);
}

// Round 11
// 324.509 us; speedup vs baseline: 1.5283x; 1.5283x over previous
//
#include <hip/hip_runtime.h>

#define BTOT 131072
#define TSEQ 15
#define BM   32

typedef __attribute__((ext_vector_type(8))) _Float16 f16x8;
typedef __attribute__((ext_vector_type(2))) __fp16 fp16x2_raw;  // builtin's return type
typedef __attribute__((ext_vector_type(4))) float f32x4;

// Activation on PRESCALED gates: gi,gf,go arrive ×(-log2 e), gg arrives ×(2 log2 e),
// folded into weights/biases, so exp2 args are the raw MFMA outputs.
__device__ __forceinline__ void lstm_act_ps(float gi, float gf, float gg, float go,
                                            float& c, float& h){
  const float P2L2E = 2.8853900817779268f;   // 2*log2(e)
  float ei = __builtin_amdgcn_exp2f(gi);
  float ef = __builtin_amdgcn_exp2f(gf);
  float eg = __builtin_amdgcn_exp2f(gg);
  float Df = 1.f + ef, Di = 1.f + ei, Dg = 1.f + eg;
  float DiDg = Di*Dg;
  float r  = __builtin_amdgcn_rcpf(Df*DiDg);
  float sf = DiDg*r;                         // sigmoid(f)
  float ig = ((eg-1.f)*Df)*r;                // sigmoid(i)*tanh(g)
  c = __builtin_fmaf(sf, c, ig);
  float eo = __builtin_amdgcn_exp2f(go);
  float ec = __builtin_amdgcn_exp2f(c * P2L2E);
  float r2 = __builtin_amdgcn_rcpf((1.f+eo)*(1.f+ec));
  h = (ec-1.f)*r2;                           // sigmoid(o)*tanh(c)
}

// pack 2 f32 -> 2 f16 (1 instr) and store to two swizzled LDS rows
__device__ __forceinline__ void store_h2(char* base, int row0, int colb,
                                         float v0, float v1){
  union { fp16x2_raw h; unsigned u; } p;
  p.h = __builtin_amdgcn_cvt_pkrtz(v0, v1);
  int off0 = (( row0   *128 + colb) ^ (( row0   &7)<<4));
  int off1 = (((row0+1)*128 + colb) ^ (((row0+1)&7)<<4));
  *(short*)(base + off0) = (short)(p.u & 0xffffu);
  *(short*)(base + off1) = (short)(p.u >> 16);
}

// ---------------- kernel 1: per-timestep batch statistics ----------------
#define RPB 512
__global__ __launch_bounds__(256) void bn_stats(const float* __restrict__ x,
                                                float* __restrict__ sums){
  __shared__ float buf[RPB*TSEQ];            // 30720 B
  const int tid = threadIdx.x;
  const float4* src = (const float4*)(x + (size_t)blockIdx.x * (RPB*TSEQ));
  float4* dst = (float4*)buf;
  #pragma unroll
  for (int i=0;i<8;i++){
    int idx = tid + i*256;
    if (idx < RPB*TSEQ/4) dst[idx] = src[idx];
  }
  __syncthreads();
  float s[TSEQ], s2[TSEQ];
  #pragma unroll
  for (int t=0;t<TSEQ;t++){ s[t]=0.f; s2[t]=0.f; }
  #pragma unroll
  for (int rr=0; rr<RPB/256; rr++){
    const float* row = buf + (tid*(RPB/256)+rr)*TSEQ;
    #pragma unroll
    for (int t=0;t<TSEQ;t++){ float v=row[t]; s[t]+=v; s2[t]=__builtin_fmaf(v,v,s2[t]); }
  }
  #pragma unroll
  for (int t=0;t<TSEQ;t++){
    #pragma unroll
    for (int off=32; off>0; off>>=1){
      s[t]  += __shfl_down(s[t],  off, 64);
      s2[t] += __shfl_down(s2[t], off, 64);
    }
  }
  __syncthreads();                           // buf reads done; reuse for partials
  const int w = tid>>6, lane = tid&63;
  if (lane==0){
    #pragma unroll
    for (int t=0;t<TSEQ;t++){ buf[w*32+t]=s[t]; buf[w*32+16+t]=s2[t]; }
  }
  __syncthreads();
  if (tid < 2*TSEQ){
    int g = (tid < TSEQ) ? tid : (tid - TSEQ + 16);
    float a = buf[g] + buf[32+g] + buf[64+g] + buf[96+g];
    atomicAdd(&sums[tid], a);
  }
}

// ---------------- kernel 2: fused BN + 2-layer LSTM + FC ----------------
// Region t computes L1(t-1) THEN L0(t) reusing ONE acc set, ONE barrier/step.
// Issue-slot trims: shared h0 A-frags (L1 & L0 read identical LDS data),
// bias-as-MFMA-C-operand (kills 32 movs/step), xns transposed for b128 loads,
// s_setprio around MFMA clusters (2 phase-drifted blocks/CU arbitrate).
// INVARIANTS (hard-won): __launch_bounds__(256,2) EXACTLY — removing it
// balloons to 176 VGPR / 1 block/CU (round 10); (256,3) spills (round 2).
// ONE live acc set (rounds 4/5 spilled with two); BM=32 (round 8 spilled).
__global__ __launch_bounds__(256, 2) void lstm_fused(
    const float* __restrict__ x,
    const float* __restrict__ gamma, const float* __restrict__ beta,
    const float* __restrict__ Wih0,  const float* __restrict__ Whh0,
    const float* __restrict__ bih0,  const float* __restrict__ bhh0,
    const float* __restrict__ Wih1,  const float* __restrict__ Whh1,
    const float* __restrict__ bih1,  const float* __restrict__ bhh1,
    const float* __restrict__ Wfc,   const float* __restrict__ bfc,
    const float* __restrict__ sums,  float* __restrict__ out)
{
  // double-buffered h tiles (f16): h0(t)->h0s[(t&1)*2048]; row stride 128B, XOR-swizzled
  __shared__ alignas(16) short h0s[2*BM*64];
  __shared__ alignas(16) short h1s[2*BM*64];
  __shared__ alignas(16) float xnsT[TSEQ][36]; // transposed; 144B row stride, 16B-aligned
  __shared__ float scs[TSEQ], shs[TSEQ];

  const int tid  = threadIdx.x;
  const int w    = tid >> 6;        // wave id 0..3 -> owns h columns [w*16, w*16+16)
  const int lane = tid & 63;
  const int l15  = lane & 15;
  const int lg   = lane >> 4;
  const int rbase = blockIdx.x * BM;

  if (tid < TSEQ){
    const float inv = 1.f/(float)BTOT;
    float mean = sums[tid]*inv;
    float var  = sums[TSEQ+tid]*inv - mean*mean;
    float sc = gamma[tid] * rsqrtf(var + 1e-5f);
    scs[tid] = sc;
    shs[tid] = beta[tid] - mean*sc;
  }
  // only h1(-1) (odd buffer of h1s) is read before being written
  #pragma unroll
  for (int i=0;i<8;i++) h1s[2048 + tid + i*256] = 0;
  __syncthreads();
  for (int i = tid; i < BM*TSEQ; i += 256){
    int r = i/TSEQ, t = i - r*TSEQ;
    xnsT[t][r] = x[(rbase+r)*TSEQ + t] * scs[t] + shs[t];
  }

  // ---- per-lane constants & weight B-fragments (registers, f16, PRESCALED) ----
  const float NL2E = -1.4426950408889634f, P2L2E = 2.8853900817779268f;
  float wx0[4], bs0[4];
  f32x4 biasC1[4];                  // L1 bias as resident MFMA C-operand
  f16x8 wB0[2][4], wB1[4][4];
  #pragma unroll
  for (int n=0;n<4;n++){
    const float ks = (n==2) ? P2L2E : NL2E;  // gate order i,f,g,o
    int g = n*64 + w*16 + l15;               // gate column (block n)
    wx0[n] = Wih0[g]*ks;
    bs0[n] = (bih0[g] + bhh0[g])*ks;
    float b1 = (bih1[g] + bhh1[g])*ks;
    biasC1[n] = (f32x4){b1, b1, b1, b1};
    #pragma unroll
    for (int kk=0;kk<2;kk++){
      const float* p = Whh0 + g*64 + kk*32 + lg*8;
      #pragma unroll
      for (int e=0;e<8;e++) wB0[kk][n][e] = (_Float16)(p[e]*ks);
    }
    #pragma unroll
    for (int kk=0;kk<4;kk++){                // combined K=128: [W_ih1 | W_hh1]
      const float* bsrc = (kk<2) ? Wih1 : Whh1;
      const float* p = bsrc + g*64 + (kk&1)*32 + lg*8;
      #pragma unroll
      for (int e=0;e<8;e++) wB1[kk][n][e] = (_Float16)(p[e]*ks);
    }
  }

  // cell state in MFMA C-layout: row = m*16 + lg*4 + r, col = w*16 + l15
  f32x4 c0[2], c1[2];
  #pragma unroll
  for (int m=0;m<2;m++){
    c0[m] = (f32x4){0.f,0.f,0.f,0.f};
    c1[m] = (f32x4){0.f,0.f,0.f,0.f};
  }

  const int colb = (w*16 + l15)*2;           // write column byte offset

  __syncthreads();

  // ---- prologue: layer0(t=0), h0(-1)=0 so no recurrent MFMA; h0(0)->h0s[0]
  #pragma unroll
  for (int m=0;m<2;m++){
    f32x4 xv = *(const f32x4*)&xnsT[0][m*16 + lg*4];
    float hv[4];
    #pragma unroll
    for (int r=0;r<4;r++){
      float g0 = __builtin_fmaf(xv[r], wx0[0], bs0[0]);
      float g1 = __builtin_fmaf(xv[r], wx0[1], bs0[1]);
      float g2 = __builtin_fmaf(xv[r], wx0[2], bs0[2]);
      float g3 = __builtin_fmaf(xv[r], wx0[3], bs0[3]);
      float c = c0[m][r];
      lstm_act_ps(g0, g1, g2, g3, c, hv[r]);
      c0[m][r] = c;
    }
    int row0 = m*16 + lg*4;
    store_h2((char*)h0s, row0,   colb, hv[0], hv[1]);
    store_h2((char*)h0s, row0+2, colb, hv[2], hv[3]);
  }
  __syncthreads();

  // ---- main loop: region t = L1(t-1) then L0(t), ONE barrier, ONE acc set ----
  #pragma unroll 2
  for (int t=1; t<TSEQ; t++){
    const int b0r = ((t-1)&1)*2048;   // h0(t-1)
    const int b0w = (t&1)*2048;       // h0(t)
    const int b1r = (t&1)*2048;       // h1(t-2)
    const int b1w = ((t-1)&1)*2048;   // h1(t-1)

    // shared h0(t-1) A-fragments: used by L1 (kk=0,1) AND L0 (both kk)
    f16x8 af0[2][2];
    #pragma unroll
    for (int kk=0;kk<2;kk++){
      #pragma unroll
      for (int m=0;m<2;m++){
        int row = m*16 + l15;
        int off = ((row*128 + kk*64 + lg*16) ^ ((row&7)<<4));
        af0[kk][m] = *(const f16x8*)((const char*)(h0s+b0r) + off);
      }
    }
    {
      // ----- layer1(t-1): gates = biasC1 + [h0(t-1) | h1(t-2)] @ [Wih1|Whh1]^T
      f32x4 acc[2][4];
      __builtin_amdgcn_s_setprio(1);
      #pragma unroll
      for (int m=0;m<2;m++)
        #pragma unroll
        for (int n=0;n<4;n++)
          acc[m][n] = __builtin_amdgcn_mfma_f32_16x16x32_f16(af0[0][m], wB1[0][n], biasC1[n], 0,0,0);
      #pragma unroll
      for (int m=0;m<2;m++)
        #pragma unroll
        for (int n=0;n<4;n++)
          acc[m][n] = __builtin_amdgcn_mfma_f32_16x16x32_f16(af0[1][m], wB1[1][n], acc[m][n], 0,0,0);
      #pragma unroll
      for (int kk=2;kk<4;kk++){
        #pragma unroll
        for (int m=0;m<2;m++){
          int row = m*16 + l15;
          int off = ((row*128 + (kk&1)*64 + lg*16) ^ ((row&7)<<4));
          f16x8 a = *(const f16x8*)((const char*)(h1s+b1r) + off);
          #pragma unroll
          for (int n=0;n<4;n++)
            acc[m][n] = __builtin_amdgcn_mfma_f32_16x16x32_f16(a, wB1[kk][n], acc[m][n], 0,0,0);
        }
      }
      __builtin_amdgcn_s_setprio(0);
      #pragma unroll
      for (int m=0;m<2;m++){
        float hv[4];
        #pragma unroll
        for (int r=0;r<4;r++){
          float c = c1[m][r];
          lstm_act_ps(acc[m][0][r], acc[m][1][r], acc[m][2][r], acc[m][3][r], c, hv[r]);
          c1[m][r] = c;
        }
        int row0 = m*16 + lg*4;
        store_h2((char*)(h1s+b1w), row0,   colb, hv[0], hv[1]);
        store_h2((char*)(h1s+b1w), row0+2, colb, hv[2], hv[3]);
      }
    }
    {
      // ----- layer0(t): gates = bias + xn(t)*W_ih0 + h0(t-1) @ Whh0^T (frags reused)
      f32x4 acc[2][4];
      #pragma unroll
      for (int m=0;m<2;m++){
        f32x4 xv = *(const f32x4*)&xnsT[t][m*16 + lg*4];
        #pragma unroll
        for (int n=0;n<4;n++)
          #pragma unroll
          for (int r=0;r<4;r++)
            acc[m][n][r] = __builtin_fmaf(xv[r], wx0[n], bs0[n]);
      }
      __builtin_amdgcn_s_setprio(1);
      #pragma unroll
      for (int kk=0;kk<2;kk++)
        #pragma unroll
        for (int m=0;m<2;m++)
          #pragma unroll
          for (int n=0;n<4;n++)
            acc[m][n] = __builtin_amdgcn_mfma_f32_16x16x32_f16(af0[kk][m], wB0[kk][n], acc[m][n], 0,0,0);
      __builtin_amdgcn_s_setprio(0);
      #pragma unroll
      for (int m=0;m<2;m++){
        float hv[4];
        #pragma unroll
        for (int r=0;r<4;r++){
          float c = c0[m][r];
          lstm_act_ps(acc[m][0][r], acc[m][1][r], acc[m][2][r], acc[m][3][r], c, hv[r]);
          c0[m][r] = c;
        }
        int row0 = m*16 + lg*4;
        store_h2((char*)(h0s+b0w), row0,   colb, hv[0], hv[1]);
        store_h2((char*)(h0s+b0w), row0+2, colb, hv[2], hv[3]);
      }
    }
    __syncthreads();   // publish h1(t-1) and h0(t)
  }

  // ---- epilogue: layer1(14): reads h0(14)=h0s[0], h1(13)=h1s[2048]; writes h1(14)->h1s[0]
  {
    f32x4 acc[2][4];
    #pragma unroll
    for (int m=0;m<2;m++){
      int row = m*16 + l15;
      int off = ((row*128 + 0*64 + lg*16) ^ ((row&7)<<4));
      f16x8 a = *(const f16x8*)((const char*)h0s + off);
      #pragma unroll
      for (int n=0;n<4;n++)
        acc[m][n] = __builtin_amdgcn_mfma_f32_16x16x32_f16(a, wB1[0][n], biasC1[n], 0,0,0);
    }
    #pragma unroll
    for (int kk=1;kk<4;kk++){
      const short* asrc = (kk<2) ? (h0s+0) : (h1s+2048);
      #pragma unroll
      for (int m=0;m<2;m++){
        int row = m*16 + l15;
        int off = ((row*128 + (kk&1)*64 + lg*16) ^ ((row&7)<<4));
        f16x8 a = *(const f16x8*)((const char*)asrc + off);
        #pragma unroll
        for (int n=0;n<4;n++)
          acc[m][n] = __builtin_amdgcn_mfma_f32_16x16x32_f16(a, wB1[kk][n], acc[m][n], 0,0,0);
      }
    }
    #pragma unroll
    for (int m=0;m<2;m++){
      float hv[4];
      #pragma unroll
      for (int r=0;r<4;r++){
        float c = c1[m][r];
        lstm_act_ps(acc[m][0][r], acc[m][1][r], acc[m][2][r], acc[m][3][r], c, hv[r]);
      }
      int row0 = m*16 + lg*4;
      store_h2((char*)h1s, row0,   colb, hv[0], hv[1]);
      store_h2((char*)h1s, row0+2, colb, hv[2], hv[3]);
    }
  }
  __syncthreads();

  // ----- FC: out = relu(h1(14) @ Wfc^T + bfc); wFC loaded HERE (not loop-carried)
  f16x8 wFC[2];
  float fcb;
  {
    int o = w*16 + l15;
    fcb = bfc[o];
    #pragma unroll
    for (int kk=0;kk<2;kk++){
      const float* p = Wfc + o*64 + kk*32 + lg*8;
      #pragma unroll
      for (int e=0;e<8;e++) wFC[kk][e] = (_Float16)p[e];
    }
  }
  f32x4 accF[2];
  #pragma unroll
  for (int m=0;m<2;m++)
    #pragma unroll
    for (int r=0;r<4;r++) accF[m][r] = fcb;
  #pragma unroll
  for (int kk=0;kk<2;kk++){
    #pragma unroll
    for (int m=0;m<2;m++){
      int row = m*16 + l15;
      int off = ((row*128 + kk*64 + lg*16) ^ ((row&7)<<4));
      f16x8 a = *(const f16x8*)((const char*)h1s + off);
      accF[m] = __builtin_amdgcn_mfma_f32_16x16x32_f16(a, wFC[kk], accF[m], 0,0,0);
    }
  }
  #pragma unroll
  for (int m=0;m<2;m++){
    #pragma unroll
    for (int r=0;r<4;r++){
      float v = accF[m][r];
      v = v > 0.f ? v : 0.f;
      out[(rbase + m*16 + lg*4 + r)*64 + w*16 + l15] = v;
    }
  }
}

extern "C" void kernel_launch(void* const* d_in, const int* in_sizes, int n_in,
                              void* d_out, int out_size, void* d_ws, size_t ws_size,
                              hipStream_t stream) {
  const float* x     = (const float*)d_in[0];
  const float* gamma = (const float*)d_in[1];
  const float* beta  = (const float*)d_in[2];
  const float* Wih0  = (const float*)d_in[3];
  const float* Whh0  = (const float*)d_in[4];
  const float* bih0  = (const float*)d_in[5];
  const float* bhh0  = (const float*)d_in[6];
  const float* Wih1  = (const float*)d_in[7];
  const float* Whh1  = (const float*)d_in[8];
  const float* bih1  = (const float*)d_in[9];
  const float* bhh1  = (const float*)d_in[10];
  const float* Wfc   = (const float*)d_in[11];
  const float* bfc   = (const float*)d_in[12];
  float* sums = (float*)d_ws;
  float* out  = (float*)d_out;

  (void)hipMemsetAsync(d_ws, 0, 2*TSEQ*sizeof(float), stream);
  bn_stats<<<dim3(BTOT/RPB), dim3(256), 0, stream>>>(x, sums);
  lstm_fused<<<dim3(BTOT/BM), dim3(256), 0, stream>>>(
      x, gamma, beta, Wih0, Whh0, bih0, bhh0,
      Wih1, Whh1, bih1, bhh1, Wfc, bfc, sums, out);
}

// Round 12
// 295.392 us; speedup vs baseline: 1.6789x; 1.0986x over previous
//
#include <hip/hip_runtime.h>

#define BTOT 131072
#define TSEQ 15
#define BM   32

typedef __attribute__((ext_vector_type(8))) _Float16 f16x8;
typedef __attribute__((ext_vector_type(2))) __fp16 fp16x2_raw;  // builtin's return type
typedef __attribute__((ext_vector_type(4))) float f32x4;
typedef __attribute__((ext_vector_type(2))) float f32x2;

// Packed-pair activation on PRESCALED gates: gi,gf,go arrive ×(-log2 e),
// gg arrives ×(2 log2 e). Vector (<2 x float>) arithmetic selects
// v_pk_{add,mul,fma}_f32 on gfx950; exp2/rcp remain scalar (no packed trans).
__device__ __forceinline__ void lstm_act2(f32x2 gi, f32x2 gf, f32x2 gg, f32x2 go,
                                          f32x2& c, f32x2& h){
  const float P2L2E = 2.8853900817779268f;   // 2*log2(e)
  f32x2 ei = {__builtin_amdgcn_exp2f(gi.x), __builtin_amdgcn_exp2f(gi.y)};
  f32x2 ef = {__builtin_amdgcn_exp2f(gf.x), __builtin_amdgcn_exp2f(gf.y)};
  f32x2 eg = {__builtin_amdgcn_exp2f(gg.x), __builtin_amdgcn_exp2f(gg.y)};
  f32x2 Df = ef + 1.f;
  f32x2 DiDg = (ei + 1.f)*(eg + 1.f);
  f32x2 P  = Df*DiDg;
  f32x2 r  = {__builtin_amdgcn_rcpf(P.x), __builtin_amdgcn_rcpf(P.y)};
  f32x2 sf = DiDg*r;                         // sigmoid(f)
  f32x2 ig = ((eg - 1.f)*Df)*r;              // sigmoid(i)*tanh(g)
  c = sf*c + ig;
  f32x2 eo = {__builtin_amdgcn_exp2f(go.x), __builtin_amdgcn_exp2f(go.y)};
  f32x2 cc = c*P2L2E;
  f32x2 ec = {__builtin_amdgcn_exp2f(cc.x), __builtin_amdgcn_exp2f(cc.y)};
  f32x2 Q  = (eo + 1.f)*(ec + 1.f);
  f32x2 r2 = {__builtin_amdgcn_rcpf(Q.x), __builtin_amdgcn_rcpf(Q.y)};
  h = (ec - 1.f)*r2;                         // sigmoid(o)*tanh(c)
}

// pack 2 f32 -> 2 f16 (1 instr) and store to two swizzled LDS rows
__device__ __forceinline__ void store_h2(char* base, int row0, int colb,
                                         float v0, float v1){
  union { fp16x2_raw h; unsigned u; } p;
  p.h = __builtin_amdgcn_cvt_pkrtz(v0, v1);
  int off0 = (( row0   *128 + colb) ^ (( row0   &7)<<4));
  int off1 = (((row0+1)*128 + colb) ^ (((row0+1)&7)<<4));
  *(short*)(base + off0) = (short)(p.u & 0xffffu);
  *(short*)(base + off1) = (short)(p.u >> 16);
}

// ---------------- kernel 1: per-timestep batch statistics ----------------
#define RPB 512
__global__ __launch_bounds__(256) void bn_stats(const float* __restrict__ x,
                                                float* __restrict__ sums){
  __shared__ float buf[RPB*TSEQ];            // 30720 B
  const int tid = threadIdx.x;
  const float4* src = (const float4*)(x + (size_t)blockIdx.x * (RPB*TSEQ));
  float4* dst = (float4*)buf;
  #pragma unroll
  for (int i=0;i<8;i++){
    int idx = tid + i*256;
    if (idx < RPB*TSEQ/4) dst[idx] = src[idx];
  }
  __syncthreads();
  float s[TSEQ], s2[TSEQ];
  #pragma unroll
  for (int t=0;t<TSEQ;t++){ s[t]=0.f; s2[t]=0.f; }
  #pragma unroll
  for (int rr=0; rr<RPB/256; rr++){
    const float* row = buf + (tid*(RPB/256)+rr)*TSEQ;
    #pragma unroll
    for (int t=0;t<TSEQ;t++){ float v=row[t]; s[t]+=v; s2[t]=__builtin_fmaf(v,v,s2[t]); }
  }
  #pragma unroll
  for (int t=0;t<TSEQ;t++){
    #pragma unroll
    for (int off=32; off>0; off>>=1){
      s[t]  += __shfl_down(s[t],  off, 64);
      s2[t] += __shfl_down(s2[t], off, 64);
    }
  }
  __syncthreads();                           // buf reads done; reuse for partials
  const int w = tid>>6, lane = tid&63;
  if (lane==0){
    #pragma unroll
    for (int t=0;t<TSEQ;t++){ buf[w*32+t]=s[t]; buf[w*32+16+t]=s2[t]; }
  }
  __syncthreads();
  if (tid < 2*TSEQ){
    int g = (tid < TSEQ) ? tid : (tid - TSEQ + 16);
    float a = buf[g] + buf[32+g] + buf[64+g] + buf[96+g];
    atomicAdd(&sums[tid], a);
  }
}

// ---------------- kernel 2: fused BN + 2-layer LSTM + FC ----------------
// Region t computes L1(t-1) THEN L0(t) reusing ONE acc set, ONE barrier/step.
// Packed-f32 (VOP3P) activation pairs + vector gate-init; shared h0 A-frags;
// bias-as-MFMA-C; xnsT b128 loads; s_setprio around MFMA clusters.
// INVARIANTS (hard-won): __launch_bounds__(256,2) EXACTLY — removing it
// balloons to 176 VGPR / 1 block/CU (round 10); (256,3) spills (round 2).
// ONE live acc set (rounds 4/5 spilled with two); BM=32 (round 8 spilled).
// Occupancy is quantized 8/4/2 waves per SIMD at <=64/<=128/<=256 unified regs;
// this kernel needs ~160 -> 2 waves/SIMD is structural.
__global__ __launch_bounds__(256, 2) void lstm_fused(
    const float* __restrict__ x,
    const float* __restrict__ gamma, const float* __restrict__ beta,
    const float* __restrict__ Wih0,  const float* __restrict__ Whh0,
    const float* __restrict__ bih0,  const float* __restrict__ bhh0,
    const float* __restrict__ Wih1,  const float* __restrict__ Whh1,
    const float* __restrict__ bih1,  const float* __restrict__ bhh1,
    const float* __restrict__ Wfc,   const float* __restrict__ bfc,
    const float* __restrict__ sums,  float* __restrict__ out)
{
  // double-buffered h tiles (f16): h0(t)->h0s[(t&1)*2048]; row stride 128B, XOR-swizzled
  __shared__ alignas(16) short h0s[2*BM*64];
  __shared__ alignas(16) short h1s[2*BM*64];
  __shared__ alignas(16) float xnsT[TSEQ][36]; // transposed; 144B row stride, 16B-aligned
  __shared__ float scs[TSEQ], shs[TSEQ];

  const int tid  = threadIdx.x;
  const int w    = tid >> 6;        // wave id 0..3 -> owns h columns [w*16, w*16+16)
  const int lane = tid & 63;
  const int l15  = lane & 15;
  const int lg   = lane >> 4;
  const int rbase = blockIdx.x * BM;

  if (tid < TSEQ){
    const float inv = 1.f/(float)BTOT;
    float mean = sums[tid]*inv;
    float var  = sums[TSEQ+tid]*inv - mean*mean;
    float sc = gamma[tid] * rsqrtf(var + 1e-5f);
    scs[tid] = sc;
    shs[tid] = beta[tid] - mean*sc;
  }
  // only h1(-1) (odd buffer of h1s) is read before being written
  #pragma unroll
  for (int i=0;i<8;i++) h1s[2048 + tid + i*256] = 0;
  __syncthreads();
  for (int i = tid; i < BM*TSEQ; i += 256){
    int r = i/TSEQ, t = i - r*TSEQ;
    xnsT[t][r] = x[(rbase+r)*TSEQ + t] * scs[t] + shs[t];
  }

  // ---- per-lane constants & weight B-fragments (registers, f16, PRESCALED) ----
  const float NL2E = -1.4426950408889634f, P2L2E = 2.8853900817779268f;
  float wx0[4], bs0[4];
  f32x4 biasC1[4];                  // L1 bias as resident MFMA C-operand
  f16x8 wB0[2][4], wB1[4][4];
  #pragma unroll
  for (int n=0;n<4;n++){
    const float ks = (n==2) ? P2L2E : NL2E;  // gate order i,f,g,o
    int g = n*64 + w*16 + l15;               // gate column (block n)
    wx0[n] = Wih0[g]*ks;
    bs0[n] = (bih0[g] + bhh0[g])*ks;
    float b1 = (bih1[g] + bhh1[g])*ks;
    biasC1[n] = (f32x4){b1, b1, b1, b1};
    #pragma unroll
    for (int kk=0;kk<2;kk++){
      const float* p = Whh0 + g*64 + kk*32 + lg*8;
      #pragma unroll
      for (int e=0;e<8;e++) wB0[kk][n][e] = (_Float16)(p[e]*ks);
    }
    #pragma unroll
    for (int kk=0;kk<4;kk++){                // combined K=128: [W_ih1 | W_hh1]
      const float* bsrc = (kk<2) ? Wih1 : Whh1;
      const float* p = bsrc + g*64 + (kk&1)*32 + lg*8;
      #pragma unroll
      for (int e=0;e<8;e++) wB1[kk][n][e] = (_Float16)(p[e]*ks);
    }
  }

  // cell state (pairs): rows m*16+lg*4+{0,1} in *a, +{2,3} in *b; col w*16+l15
  f32x2 c0a[2], c0b[2], c1a[2], c1b[2];
  #pragma unroll
  for (int m=0;m<2;m++){
    c0a[m] = (f32x2){0.f,0.f}; c0b[m] = (f32x2){0.f,0.f};
    c1a[m] = (f32x2){0.f,0.f}; c1b[m] = (f32x2){0.f,0.f};
  }

  const int colb = (w*16 + l15)*2;           // write column byte offset

  __syncthreads();

  // ---- prologue: layer0(t=0), h0(-1)=0 so no recurrent MFMA; h0(0)->h0s[0]
  #pragma unroll
  for (int m=0;m<2;m++){
    f32x4 xv = *(const f32x4*)&xnsT[0][m*16 + lg*4];
    f32x4 gv[4];
    #pragma unroll
    for (int n=0;n<4;n++) gv[n] = xv*wx0[n] + bs0[n];
    f32x2 hA, hB;
    lstm_act2((f32x2){gv[0][0],gv[0][1]}, (f32x2){gv[1][0],gv[1][1]},
              (f32x2){gv[2][0],gv[2][1]}, (f32x2){gv[3][0],gv[3][1]}, c0a[m], hA);
    lstm_act2((f32x2){gv[0][2],gv[0][3]}, (f32x2){gv[1][2],gv[1][3]},
              (f32x2){gv[2][2],gv[2][3]}, (f32x2){gv[3][2],gv[3][3]}, c0b[m], hB);
    int row0 = m*16 + lg*4;
    store_h2((char*)h0s, row0,   colb, hA.x, hA.y);
    store_h2((char*)h0s, row0+2, colb, hB.x, hB.y);
  }
  __syncthreads();

  // ---- main loop: region t = L1(t-1) then L0(t), ONE barrier, ONE acc set ----
  #pragma unroll 2
  for (int t=1; t<TSEQ; t++){
    const int b0r = ((t-1)&1)*2048;   // h0(t-1)
    const int b0w = (t&1)*2048;       // h0(t)
    const int b1r = (t&1)*2048;       // h1(t-2)
    const int b1w = ((t-1)&1)*2048;   // h1(t-1)

    // shared h0(t-1) A-fragments: used by L1 (kk=0,1) AND L0 (both kk)
    f16x8 af0[2][2];
    #pragma unroll
    for (int kk=0;kk<2;kk++){
      #pragma unroll
      for (int m=0;m<2;m++){
        int row = m*16 + l15;
        int off = ((row*128 + kk*64 + lg*16) ^ ((row&7)<<4));
        af0[kk][m] = *(const f16x8*)((const char*)(h0s+b0r) + off);
      }
    }
    {
      // ----- layer1(t-1): gates = biasC1 + [h0(t-1) | h1(t-2)] @ [Wih1|Whh1]^T
      f32x4 acc[2][4];
      __builtin_amdgcn_s_setprio(1);
      #pragma unroll
      for (int m=0;m<2;m++)
        #pragma unroll
        for (int n=0;n<4;n++)
          acc[m][n] = __builtin_amdgcn_mfma_f32_16x16x32_f16(af0[0][m], wB1[0][n], biasC1[n], 0,0,0);
      #pragma unroll
      for (int m=0;m<2;m++)
        #pragma unroll
        for (int n=0;n<4;n++)
          acc[m][n] = __builtin_amdgcn_mfma_f32_16x16x32_f16(af0[1][m], wB1[1][n], acc[m][n], 0,0,0);
      #pragma unroll
      for (int kk=2;kk<4;kk++){
        #pragma unroll
        for (int m=0;m<2;m++){
          int row = m*16 + l15;
          int off = ((row*128 + (kk&1)*64 + lg*16) ^ ((row&7)<<4));
          f16x8 a = *(const f16x8*)((const char*)(h1s+b1r) + off);
          #pragma unroll
          for (int n=0;n<4;n++)
            acc[m][n] = __builtin_amdgcn_mfma_f32_16x16x32_f16(a, wB1[kk][n], acc[m][n], 0,0,0);
        }
      }
      __builtin_amdgcn_s_setprio(0);
      #pragma unroll
      for (int m=0;m<2;m++){
        f32x2 hA, hB;
        lstm_act2((f32x2){acc[m][0][0],acc[m][0][1]}, (f32x2){acc[m][1][0],acc[m][1][1]},
                  (f32x2){acc[m][2][0],acc[m][2][1]}, (f32x2){acc[m][3][0],acc[m][3][1]},
                  c1a[m], hA);
        lstm_act2((f32x2){acc[m][0][2],acc[m][0][3]}, (f32x2){acc[m][1][2],acc[m][1][3]},
                  (f32x2){acc[m][2][2],acc[m][2][3]}, (f32x2){acc[m][3][2],acc[m][3][3]},
                  c1b[m], hB);
        int row0 = m*16 + lg*4;
        store_h2((char*)(h1s+b1w), row0,   colb, hA.x, hA.y);
        store_h2((char*)(h1s+b1w), row0+2, colb, hB.x, hB.y);
      }
    }
    {
      // ----- layer0(t): gates = bias + xn(t)*W_ih0 + h0(t-1) @ Whh0^T (frags reused)
      f32x4 acc[2][4];
      #pragma unroll
      for (int m=0;m<2;m++){
        f32x4 xv = *(const f32x4*)&xnsT[t][m*16 + lg*4];
        #pragma unroll
        for (int n=0;n<4;n++)
          acc[m][n] = xv*wx0[n] + bs0[n];    // packed v_pk_fma_f32 ×2
      }
      __builtin_amdgcn_s_setprio(1);
      #pragma unroll
      for (int kk=0;kk<2;kk++)
        #pragma unroll
        for (int m=0;m<2;m++)
          #pragma unroll
          for (int n=0;n<4;n++)
            acc[m][n] = __builtin_amdgcn_mfma_f32_16x16x32_f16(af0[kk][m], wB0[kk][n], acc[m][n], 0,0,0);
      __builtin_amdgcn_s_setprio(0);
      #pragma unroll
      for (int m=0;m<2;m++){
        f32x2 hA, hB;
        lstm_act2((f32x2){acc[m][0][0],acc[m][0][1]}, (f32x2){acc[m][1][0],acc[m][1][1]},
                  (f32x2){acc[m][2][0],acc[m][2][1]}, (f32x2){acc[m][3][0],acc[m][3][1]},
                  c0a[m], hA);
        lstm_act2((f32x2){acc[m][0][2],acc[m][0][3]}, (f32x2){acc[m][1][2],acc[m][1][3]},
                  (f32x2){acc[m][2][2],acc[m][2][3]}, (f32x2){acc[m][3][2],acc[m][3][3]},
                  c0b[m], hB);
        int row0 = m*16 + lg*4;
        store_h2((char*)(h0s+b0w), row0,   colb, hA.x, hA.y);
        store_h2((char*)(h0s+b0w), row0+2, colb, hB.x, hB.y);
      }
    }
    __syncthreads();   // publish h1(t-1) and h0(t)
  }

  // ---- epilogue: layer1(14): reads h0(14)=h0s[0], h1(13)=h1s[2048]; writes h1(14)->h1s[0]
  {
    f32x4 acc[2][4];
    #pragma unroll
    for (int m=0;m<2;m++){
      int row = m*16 + l15;
      int off = ((row*128 + 0*64 + lg*16) ^ ((row&7)<<4));
      f16x8 a = *(const f16x8*)((const char*)h0s + off);
      #pragma unroll
      for (int n=0;n<4;n++)
        acc[m][n] = __builtin_amdgcn_mfma_f32_16x16x32_f16(a, wB1[0][n], biasC1[n], 0,0,0);
    }
    #pragma unroll
    for (int kk=1;kk<4;kk++){
      const short* asrc = (kk<2) ? (h0s+0) : (h1s+2048);
      #pragma unroll
      for (int m=0;m<2;m++){
        int row = m*16 + l15;
        int off = ((row*128 + (kk&1)*64 + lg*16) ^ ((row&7)<<4));
        f16x8 a = *(const f16x8*)((const char*)asrc + off);
        #pragma unroll
        for (int n=0;n<4;n++)
          acc[m][n] = __builtin_amdgcn_mfma_f32_16x16x32_f16(a, wB1[kk][n], acc[m][n], 0,0,0);
      }
    }
    #pragma unroll
    for (int m=0;m<2;m++){
      f32x2 hA, hB;
      lstm_act2((f32x2){acc[m][0][0],acc[m][0][1]}, (f32x2){acc[m][1][0],acc[m][1][1]},
                (f32x2){acc[m][2][0],acc[m][2][1]}, (f32x2){acc[m][3][0],acc[m][3][1]},
                c1a[m], hA);
      lstm_act2((f32x2){acc[m][0][2],acc[m][0][3]}, (f32x2){acc[m][1][2],acc[m][1][3]},
                (f32x2){acc[m][2][2],acc[m][2][3]}, (f32x2){acc[m][3][2],acc[m][3][3]},
                c1b[m], hB);
      int row0 = m*16 + lg*4;
      store_h2((char*)h1s, row0,   colb, hA.x, hA.y);
      store_h2((char*)h1s, row0+2, colb, hB.x, hB.y);
    }
  }
  __syncthreads();

  // ----- FC: out = relu(h1(14) @ Wfc^T + bfc); wFC loaded HERE (not loop-carried)
  f16x8 wFC[2];
  float fcb;
  {
    int o = w*16 + l15;
    fcb = bfc[o];
    #pragma unroll
    for (int kk=0;kk<2;kk++){
      const float* p = Wfc + o*64 + kk*32 + lg*8;
      #pragma unroll
      for (int e=0;e<8;e++) wFC[kk][e] = (_Float16)p[e];
    }
  }
  f32x4 accF[2];
  #pragma unroll
  for (int m=0;m<2;m++)
    #pragma unroll
    for (int r=0;r<4;r++) accF[m][r] = fcb;
  #pragma unroll
  for (int kk=0;kk<2;kk++){
    #pragma unroll
    for (int m=0;m<2;m++){
      int row = m*16 + l15;
      int off = ((row*128 + kk*64 + lg*16) ^ ((row&7)<<4));
      f16x8 a = *(const f16x8*)((const char*)h1s + off);
      accF[m] = __builtin_amdgcn_mfma_f32_16x16x32_f16(a, wFC[kk], accF[m], 0,0,0);
    }
  }
  #pragma unroll
  for (int m=0;m<2;m++){
    #pragma unroll
    for (int r=0;r<4;r++){
      float v = accF[m][r];
      v = v > 0.f ? v : 0.f;
      out[(rbase + m*16 + lg*4 + r)*64 + w*16 + l15] = v;
    }
  }
}

extern "C" void kernel_launch(void* const* d_in, const int* in_sizes, int n_in,
                              void* d_out, int out_size, void* d_ws, size_t ws_size,
                              hipStream_t stream) {
  const float* x     = (const float*)d_in[0];
  const float* gamma = (const float*)d_in[1];
  const float* beta  = (const float*)d_in[2];
  const float* Wih0  = (const float*)d_in[3];
  const float* Whh0  = (const float*)d_in[4];
  const float* bih0  = (const float*)d_in[5];
  const float* bhh0  = (const float*)d_in[6];
  const float* Wih1  = (const float*)d_in[7];
  const float* Whh1  = (const float*)d_in[8];
  const float* bih1  = (const float*)d_in[9];
  const float* bhh1  = (const float*)d_in[10];
  const float* Wfc   = (const float*)d_in[11];
  const float* bfc   = (const float*)d_in[12];
  float* sums = (float*)d_ws;
  float* out  = (float*)d_out;

  (void)hipMemsetAsync(d_ws, 0, 2*TSEQ*sizeof(float), stream);
  bn_stats<<<dim3(BTOT/RPB), dim3(256), 0, stream>>>(x, sums);
  lstm_fused<<<dim3(BTOT/BM), dim3(256), 0, stream>>>(
      x, gamma, beta, Wih0, Whh0, bih0, bhh0,
      Wih1, Whh1, bih1, bhh1, Wfc, bfc, sums, out);
}

// Round 13
// 294.661 us; speedup vs baseline: 1.6831x; 1.0025x over previous
//
#include <hip/hip_runtime.h>

#define BTOT 131072
#define TSEQ 15
#define BM   32

typedef __attribute__((ext_vector_type(8))) _Float16 f16x8;
typedef __attribute__((ext_vector_type(2))) __fp16 fp16x2_raw;  // builtin's return type
typedef __attribute__((ext_vector_type(4))) float f32x4;
typedef __attribute__((ext_vector_type(2))) float f32x2;

// Packed-pair activation on PRESCALED gates: gi,gf,go arrive ×(-log2 e),
// gg arrives ×(2 log2 e). Vector (<2 x float>) arithmetic selects
// v_pk_{add,mul,fma}_f32 on gfx950; exp2/rcp remain scalar (no packed trans).
__device__ __forceinline__ void lstm_act2(f32x2 gi, f32x2 gf, f32x2 gg, f32x2 go,
                                          f32x2& c, f32x2& h){
  const float P2L2E = 2.8853900817779268f;   // 2*log2(e)
  f32x2 ei = {__builtin_amdgcn_exp2f(gi.x), __builtin_amdgcn_exp2f(gi.y)};
  f32x2 ef = {__builtin_amdgcn_exp2f(gf.x), __builtin_amdgcn_exp2f(gf.y)};
  f32x2 eg = {__builtin_amdgcn_exp2f(gg.x), __builtin_amdgcn_exp2f(gg.y)};
  f32x2 Df = ef + 1.f;
  f32x2 DiDg = (ei + 1.f)*(eg + 1.f);
  f32x2 P  = Df*DiDg;
  f32x2 r  = {__builtin_amdgcn_rcpf(P.x), __builtin_amdgcn_rcpf(P.y)};
  f32x2 sf = DiDg*r;                         // sigmoid(f)
  f32x2 ig = ((eg - 1.f)*Df)*r;              // sigmoid(i)*tanh(g)
  c = sf*c + ig;
  f32x2 eo = {__builtin_amdgcn_exp2f(go.x), __builtin_amdgcn_exp2f(go.y)};
  f32x2 cc = c*P2L2E;
  f32x2 ec = {__builtin_amdgcn_exp2f(cc.x), __builtin_amdgcn_exp2f(cc.y)};
  f32x2 Q  = (eo + 1.f)*(ec + 1.f);
  f32x2 r2 = {__builtin_amdgcn_rcpf(Q.x), __builtin_amdgcn_rcpf(Q.y)};
  h = (ec - 1.f)*r2;                         // sigmoid(o)*tanh(c)
}

// pack 2 f32 -> 2 f16 (1 instr) and store to two swizzled LDS rows
__device__ __forceinline__ void store_h2(char* base, int row0, int colb,
                                         float v0, float v1){
  union { fp16x2_raw h; unsigned u; } p;
  p.h = __builtin_amdgcn_cvt_pkrtz(v0, v1);
  int off0 = (( row0   *128 + colb) ^ (( row0   &7)<<4));
  int off1 = (((row0+1)*128 + colb) ^ (((row0+1)&7)<<4));
  *(short*)(base + off0) = (short)(p.u & 0xffffu);
  *(short*)(base + off1) = (short)(p.u >> 16);
}

// ---------------- kernel 1: per-timestep batch statistics ----------------
#define RPB 512
__global__ __launch_bounds__(256) void bn_stats(const float* __restrict__ x,
                                                float* __restrict__ sums){
  __shared__ float buf[RPB*TSEQ];            // 30720 B
  const int tid = threadIdx.x;
  const float4* src = (const float4*)(x + (size_t)blockIdx.x * (RPB*TSEQ));
  float4* dst = (float4*)buf;
  #pragma unroll
  for (int i=0;i<8;i++){
    int idx = tid + i*256;
    if (idx < RPB*TSEQ/4) dst[idx] = src[idx];
  }
  __syncthreads();
  float s[TSEQ], s2[TSEQ];
  #pragma unroll
  for (int t=0;t<TSEQ;t++){ s[t]=0.f; s2[t]=0.f; }
  #pragma unroll
  for (int rr=0; rr<RPB/256; rr++){
    const float* row = buf + (tid*(RPB/256)+rr)*TSEQ;
    #pragma unroll
    for (int t=0;t<TSEQ;t++){ float v=row[t]; s[t]+=v; s2[t]=__builtin_fmaf(v,v,s2[t]); }
  }
  #pragma unroll
  for (int t=0;t<TSEQ;t++){
    #pragma unroll
    for (int off=32; off>0; off>>=1){
      s[t]  += __shfl_down(s[t],  off, 64);
      s2[t] += __shfl_down(s2[t], off, 64);
    }
  }
  __syncthreads();                           // buf reads done; reuse for partials
  const int w = tid>>6, lane = tid&63;
  if (lane==0){
    #pragma unroll
    for (int t=0;t<TSEQ;t++){ buf[w*32+t]=s[t]; buf[w*32+16+t]=s2[t]; }
  }
  __syncthreads();
  if (tid < 2*TSEQ){
    int g = (tid < TSEQ) ? tid : (tid - TSEQ + 16);
    float a = buf[g] + buf[32+g] + buf[64+g] + buf[96+g];
    atomicAdd(&sums[tid], a);
  }
}

// ---------------- kernel 2: fused BN + 2-layer LSTM + FC ----------------
// Region t computes L1(t-1) THEN L0(t) reusing ONE acc set, ONE barrier/step.
// Packed-f32 (VOP3P) activation pairs + vector gate-init; shared h0 A-frags;
// bias-as-MFMA-C; xnsT b128 loads; s_setprio around MFMA clusters.
// INVARIANTS (hard-won): __launch_bounds__(256,2) EXACTLY — removing it
// balloons to 176 VGPR / 1 block/CU (round 10); (256,3) spills (round 2).
// ONE live acc set (rounds 4/5 spilled with two); BM=32 (round 8 spilled).
// Occupancy is quantized 8/4/2 waves per SIMD at <=64/<=128/<=256 unified regs;
// this kernel needs ~160 -> 2 waves/SIMD is structural.
__global__ __launch_bounds__(256, 2) void lstm_fused(
    const float* __restrict__ x,
    const float* __restrict__ gamma, const float* __restrict__ beta,
    const float* __restrict__ Wih0,  const float* __restrict__ Whh0,
    const float* __restrict__ bih0,  const float* __restrict__ bhh0,
    const float* __restrict__ Wih1,  const float* __restrict__ Whh1,
    const float* __restrict__ bih1,  const float* __restrict__ bhh1,
    const float* __restrict__ Wfc,   const float* __restrict__ bfc,
    const float* __restrict__ sums,  float* __restrict__ out)
{
  // double-buffered h tiles (f16): h0(t)->h0s[(t&1)*2048]; row stride 128B, XOR-swizzled
  __shared__ alignas(16) short h0s[2*BM*64];
  __shared__ alignas(16) short h1s[2*BM*64];
  __shared__ alignas(16) float xnsT[TSEQ][36]; // transposed; 144B row stride, 16B-aligned
  __shared__ float scs[TSEQ], shs[TSEQ];

  const int tid  = threadIdx.x;
  const int w    = tid >> 6;        // wave id 0..3 -> owns h columns [w*16, w*16+16)
  const int lane = tid & 63;
  const int l15  = lane & 15;
  const int lg   = lane >> 4;
  const int rbase = blockIdx.x * BM;

  if (tid < TSEQ){
    const float inv = 1.f/(float)BTOT;
    float mean = sums[tid]*inv;
    float var  = sums[TSEQ+tid]*inv - mean*mean;
    float sc = gamma[tid] * rsqrtf(var + 1e-5f);
    scs[tid] = sc;
    shs[tid] = beta[tid] - mean*sc;
  }
  // only h1(-1) (odd buffer of h1s) is read before being written
  #pragma unroll
  for (int i=0;i<8;i++) h1s[2048 + tid + i*256] = 0;
  __syncthreads();
  for (int i = tid; i < BM*TSEQ; i += 256){
    int r = i/TSEQ, t = i - r*TSEQ;
    xnsT[t][r] = x[(rbase+r)*TSEQ + t] * scs[t] + shs[t];
  }

  // ---- per-lane constants & weight B-fragments (registers, f16, PRESCALED) ----
  const float NL2E = -1.4426950408889634f, P2L2E = 2.8853900817779268f;
  float wx0[4], bs0[4];
  f32x4 biasC1[4];                  // L1 bias as resident MFMA C-operand
  f16x8 wB0[2][4], wB1[4][4];
  #pragma unroll
  for (int n=0;n<4;n++){
    const float ks = (n==2) ? P2L2E : NL2E;  // gate order i,f,g,o
    int g = n*64 + w*16 + l15;               // gate column (block n)
    wx0[n] = Wih0[g]*ks;
    bs0[n] = (bih0[g] + bhh0[g])*ks;
    float b1 = (bih1[g] + bhh1[g])*ks;
    biasC1[n] = (f32x4){b1, b1, b1, b1};
    #pragma unroll
    for (int kk=0;kk<2;kk++){
      const float* p = Whh0 + g*64 + kk*32 + lg*8;
      #pragma unroll
      for (int e=0;e<8;e++) wB0[kk][n][e] = (_Float16)(p[e]*ks);
    }
    #pragma unroll
    for (int kk=0;kk<4;kk++){                // combined K=128: [W_ih1 | W_hh1]
      const float* bsrc = (kk<2) ? Wih1 : Whh1;
      const float* p = bsrc + g*64 + (kk&1)*32 + lg*8;
      #pragma unroll
      for (int e=0;e<8;e++) wB1[kk][n][e] = (_Float16)(p[e]*ks);
    }
  }

  // cell state (pairs): rows m*16+lg*4+{0,1} in *a, +{2,3} in *b; col w*16+l15
  f32x2 c0a[2], c0b[2], c1a[2], c1b[2];
  #pragma unroll
  for (int m=0;m<2;m++){
    c0a[m] = (f32x2){0.f,0.f}; c0b[m] = (f32x2){0.f,0.f};
    c1a[m] = (f32x2){0.f,0.f}; c1b[m] = (f32x2){0.f,0.f};
  }

  const int colb = (w*16 + l15)*2;           // write column byte offset

  __syncthreads();

  // ---- prologue: layer0(t=0), h0(-1)=0 so no recurrent MFMA; h0(0)->h0s[0]
  #pragma unroll
  for (int m=0;m<2;m++){
    f32x4 xv = *(const f32x4*)&xnsT[0][m*16 + lg*4];
    f32x4 gv[4];
    #pragma unroll
    for (int n=0;n<4;n++) gv[n] = xv*wx0[n] + bs0[n];
    f32x2 hA, hB;
    lstm_act2((f32x2){gv[0][0],gv[0][1]}, (f32x2){gv[1][0],gv[1][1]},
              (f32x2){gv[2][0],gv[2][1]}, (f32x2){gv[3][0],gv[3][1]}, c0a[m], hA);
    lstm_act2((f32x2){gv[0][2],gv[0][3]}, (f32x2){gv[1][2],gv[1][3]},
              (f32x2){gv[2][2],gv[2][3]}, (f32x2){gv[3][2],gv[3][3]}, c0b[m], hB);
    int row0 = m*16 + lg*4;
    store_h2((char*)h0s, row0,   colb, hA.x, hA.y);
    store_h2((char*)h0s, row0+2, colb, hB.x, hB.y);
  }
  __syncthreads();

  // ---- main loop: region t = L1(t-1) then L0(t), ONE barrier, ONE acc set ----
  #pragma unroll 2
  for (int t=1; t<TSEQ; t++){
    const int b0r = ((t-1)&1)*2048;   // h0(t-1)
    const int b0w = (t&1)*2048;       // h0(t)
    const int b1r = (t&1)*2048;       // h1(t-2)
    const int b1w = ((t-1)&1)*2048;   // h1(t-1)

    // shared h0(t-1) A-fragments: used by L1 (kk=0,1) AND L0 (both kk)
    f16x8 af0[2][2];
    #pragma unroll
    for (int kk=0;kk<2;kk++){
      #pragma unroll
      for (int m=0;m<2;m++){
        int row = m*16 + l15;
        int off = ((row*128 + kk*64 + lg*16) ^ ((row&7)<<4));
        af0[kk][m] = *(const f16x8*)((const char*)(h0s+b0r) + off);
      }
    }
    {
      // ----- layer1(t-1): gates = biasC1 + [h0(t-1) | h1(t-2)] @ [Wih1|Whh1]^T
      f32x4 acc[2][4];
      __builtin_amdgcn_s_setprio(1);
      #pragma unroll
      for (int m=0;m<2;m++)
        #pragma unroll
        for (int n=0;n<4;n++)
          acc[m][n] = __builtin_amdgcn_mfma_f32_16x16x32_f16(af0[0][m], wB1[0][n], biasC1[n], 0,0,0);
      #pragma unroll
      for (int m=0;m<2;m++)
        #pragma unroll
        for (int n=0;n<4;n++)
          acc[m][n] = __builtin_amdgcn_mfma_f32_16x16x32_f16(af0[1][m], wB1[1][n], acc[m][n], 0,0,0);
      #pragma unroll
      for (int kk=2;kk<4;kk++){
        #pragma unroll
        for (int m=0;m<2;m++){
          int row = m*16 + l15;
          int off = ((row*128 + (kk&1)*64 + lg*16) ^ ((row&7)<<4));
          f16x8 a = *(const f16x8*)((const char*)(h1s+b1r) + off);
          #pragma unroll
          for (int n=0;n<4;n++)
            acc[m][n] = __builtin_amdgcn_mfma_f32_16x16x32_f16(a, wB1[kk][n], acc[m][n], 0,0,0);
        }
      }
      __builtin_amdgcn_s_setprio(0);
      #pragma unroll
      for (int m=0;m<2;m++){
        f32x2 hA, hB;
        lstm_act2((f32x2){acc[m][0][0],acc[m][0][1]}, (f32x2){acc[m][1][0],acc[m][1][1]},
                  (f32x2){acc[m][2][0],acc[m][2][1]}, (f32x2){acc[m][3][0],acc[m][3][1]},
                  c1a[m], hA);
        lstm_act2((f32x2){acc[m][0][2],acc[m][0][3]}, (f32x2){acc[m][1][2],acc[m][1][3]},
                  (f32x2){acc[m][2][2],acc[m][2][3]}, (f32x2){acc[m][3][2],acc[m][3][3]},
                  c1b[m], hB);
        int row0 = m*16 + lg*4;
        store_h2((char*)(h1s+b1w), row0,   colb, hA.x, hA.y);
        store_h2((char*)(h1s+b1w), row0+2, colb, hB.x, hB.y);
      }
    }
    {
      // ----- layer0(t): gates = bias + xn(t)*W_ih0 + h0(t-1) @ Whh0^T (frags reused)
      f32x4 acc[2][4];
      #pragma unroll
      for (int m=0;m<2;m++){
        f32x4 xv = *(const f32x4*)&xnsT[t][m*16 + lg*4];
        #pragma unroll
        for (int n=0;n<4;n++)
          acc[m][n] = xv*wx0[n] + bs0[n];    // packed v_pk_fma_f32 ×2
      }
      __builtin_amdgcn_s_setprio(1);
      #pragma unroll
      for (int kk=0;kk<2;kk++)
        #pragma unroll
        for (int m=0;m<2;m++)
          #pragma unroll
          for (int n=0;n<4;n++)
            acc[m][n] = __builtin_amdgcn_mfma_f32_16x16x32_f16(af0[kk][m], wB0[kk][n], acc[m][n], 0,0,0);
      __builtin_amdgcn_s_setprio(0);
      #pragma unroll
      for (int m=0;m<2;m++){
        f32x2 hA, hB;
        lstm_act2((f32x2){acc[m][0][0],acc[m][0][1]}, (f32x2){acc[m][1][0],acc[m][1][1]},
                  (f32x2){acc[m][2][0],acc[m][2][1]}, (f32x2){acc[m][3][0],acc[m][3][1]},
                  c0a[m], hA);
        lstm_act2((f32x2){acc[m][0][2],acc[m][0][3]}, (f32x2){acc[m][1][2],acc[m][1][3]},
                  (f32x2){acc[m][2][2],acc[m][2][3]}, (f32x2){acc[m][3][2],acc[m][3][3]},
                  c0b[m], hB);
        int row0 = m*16 + lg*4;
        store_h2((char*)(h0s+b0w), row0,   colb, hA.x, hA.y);
        store_h2((char*)(h0s+b0w), row0+2, colb, hB.x, hB.y);
      }
    }
    __syncthreads();   // publish h1(t-1) and h0(t)
  }

  // ---- epilogue: layer1(14): reads h0(14)=h0s[0], h1(13)=h1s[2048]; writes h1(14)->h1s[0]
  {
    f32x4 acc[2][4];
    #pragma unroll
    for (int m=0;m<2;m++){
      int row = m*16 + l15;
      int off = ((row*128 + 0*64 + lg*16) ^ ((row&7)<<4));
      f16x8 a = *(const f16x8*)((const char*)h0s + off);
      #pragma unroll
      for (int n=0;n<4;n++)
        acc[m][n] = __builtin_amdgcn_mfma_f32_16x16x32_f16(a, wB1[0][n], biasC1[n], 0,0,0);
    }
    #pragma unroll
    for (int kk=1;kk<4;kk++){
      const short* asrc = (kk<2) ? (h0s+0) : (h1s+2048);
      #pragma unroll
      for (int m=0;m<2;m++){
        int row = m*16 + l15;
        int off = ((row*128 + (kk&1)*64 + lg*16) ^ ((row&7)<<4));
        f16x8 a = *(const f16x8*)((const char*)asrc + off);
        #pragma unroll
        for (int n=0;n<4;n++)
          acc[m][n] = __builtin_amdgcn_mfma_f32_16x16x32_f16(a, wB1[kk][n], acc[m][n], 0,0,0);
      }
    }
    #pragma unroll
    for (int m=0;m<2;m++){
      f32x2 hA, hB;
      lstm_act2((f32x2){acc[m][0][0],acc[m][0][1]}, (f32x2){acc[m][1][0],acc[m][1][1]},
                (f32x2){acc[m][2][0],acc[m][2][1]}, (f32x2){acc[m][3][0],acc[m][3][1]},
                c1a[m], hA);
      lstm_act2((f32x2){acc[m][0][2],acc[m][0][3]}, (f32x2){acc[m][1][2],acc[m][1][3]},
                (f32x2){acc[m][2][2],acc[m][2][3]}, (f32x2){acc[m][3][2],acc[m][3][3]},
                c1b[m], hB);
      int row0 = m*16 + lg*4;
      store_h2((char*)h1s, row0,   colb, hA.x, hA.y);
      store_h2((char*)h1s, row0+2, colb, hB.x, hB.y);
    }
  }
  __syncthreads();

  // ----- FC: out = relu(h1(14) @ Wfc^T + bfc); wFC loaded HERE (not loop-carried)
  f16x8 wFC[2];
  float fcb;
  {
    int o = w*16 + l15;
    fcb = bfc[o];
    #pragma unroll
    for (int kk=0;kk<2;kk++){
      const float* p = Wfc + o*64 + kk*32 + lg*8;
      #pragma unroll
      for (int e=0;e<8;e++) wFC[kk][e] = (_Float16)p[e];
    }
  }
  f32x4 accF[2];
  #pragma unroll
  for (int m=0;m<2;m++)
    #pragma unroll
    for (int r=0;r<4;r++) accF[m][r] = fcb;
  #pragma unroll
  for (int kk=0;kk<2;kk++){
    #pragma unroll
    for (int m=0;m<2;m++){
      int row = m*16 + l15;
      int off = ((row*128 + kk*64 + lg*16) ^ ((row&7)<<4));
      f16x8 a = *(const f16x8*)((const char*)h1s + off);
      accF[m] = __builtin_amdgcn_mfma_f32_16x16x32_f16(a, wFC[kk], accF[m], 0,0,0);
    }
  }
  #pragma unroll
  for (int m=0;m<2;m++){
    #pragma unroll
    for (int r=0;r<4;r++){
      float v = accF[m][r];
      v = v > 0.f ? v : 0.f;
      out[(rbase + m*16 + lg*4 + r)*64 + w*16 + l15] = v;
    }
  }
}

extern "C" void kernel_launch(void* const* d_in, const int* in_sizes, int n_in,
                              void* d_out, int out_size, void* d_ws, size_t ws_size,
                              hipStream_t stream) {
  const float* x     = (const float*)d_in[0];
  const float* gamma = (const float*)d_in[1];
  const float* beta  = (const float*)d_in[2];
  const float* Wih0  = (const float*)d_in[3];
  const float* Whh0  = (const float*)d_in[4];
  const float* bih0  = (const float*)d_in[5];
  const float* bhh0  = (const float*)d_in[6];
  const float* Wih1  = (const float*)d_in[7];
  const float* Whh1  = (const float*)d_in[8];
  const float* bih1  = (const float*)d_in[9];
  const float* bhh1  = (const float*)d_in[10];
  const float* Wfc   = (const float*)d_in[11];
  const float* bfc   = (const float*)d_in[12];
  float* sums = (float*)d_ws;
  float* out  = (float*)d_out;

  (void)hipMemsetAsync(d_ws, 0, 2*TSEQ*sizeof(float), stream);
  bn_stats<<<dim3(BTOT/RPB), dim3(256), 0, stream>>>(x, sums);
  lstm_fused<<<dim3(BTOT/BM), dim3(256), 0, stream>>>(
      x, gamma, beta, Wih0, Whh0, bih0, bhh0,
      Wih1, Whh1, bih1, bhh1, Wfc, bfc, sums, out);
}